// Round 3
// baseline (275.910 us; speedup 1.0000x reference)
//
#include <hip/hip_runtime.h>
#include <hip/hip_bf16.h>

#define BS    8
#define NQ    16384
#define CDIM  128
#define NH    8
#define NP    4
#define HD    16
#define RES   128
#define NPROJ 224            // 128 value + 64 off + 32 attn logits
#define M_TOTAL (BS*NQ)      // 131072 rows

typedef __bf16 bf16_t;
typedef __bf16 bf16x8 __attribute__((ext_vector_type(8)));
typedef __bf16 bf16x4 __attribute__((ext_vector_type(4)));
typedef float  f32x4  __attribute__((ext_vector_type(4)));
typedef unsigned int u32;

__device__ __forceinline__ bf16x8 cvt_bf16x8(const float* p) {
    float4 a = *(const float4*)p;
    float4 b = *(const float4*)(p + 4);
    bf16x8 r;
    r[0] = (bf16_t)a.x; r[1] = (bf16_t)a.y; r[2] = (bf16_t)a.z; r[3] = (bf16_t)a.w;
    r[4] = (bf16_t)b.x; r[5] = (bf16_t)b.y; r[6] = (bf16_t)b.z; r[7] = (bf16_t)b.w;
    return r;
}

// ---------------------------------------------------------------------------
// Kernel 1: fused projections  P = query @ [Wv | Woff | Wattn] + bias
//   cols   0..127 -> value (bf16, ws)
//   cols 128..191 -> offsets (fp32, ws)
//   cols 192..223 -> attn logits (fp32, ws)
// ---------------------------------------------------------------------------
__global__ __launch_bounds__(256, 2)
void proj_kernel(const float* __restrict__ query,
                 const float* __restrict__ Wv,    const float* __restrict__ bv,
                 const float* __restrict__ Woff,  const float* __restrict__ boff,
                 const float* __restrict__ Wattn, const float* __restrict__ battn,
                 bf16_t* __restrict__ value, float* __restrict__ off,
                 float* __restrict__ attnl)
{
    __shared__ bf16_t Bt[NPROJ][136];   // transposed weights (bf16), padded
    __shared__ float  bias[NPROJ];
    const int t = threadIdx.x;

    for (int i = t; i < 128*128; i += 256) { int k = i >> 7, n = i & 127; Bt[n][k]     = (bf16_t)Wv[i]; }
    for (int i = t; i < 128*64;  i += 256) { int k = i >> 6, n = i & 63;  Bt[128+n][k] = (bf16_t)Woff[i]; }
    for (int i = t; i < 128*32;  i += 256) { int k = i >> 5, n = i & 31;  Bt[192+n][k] = (bf16_t)Wattn[i]; }
    if (t < 128)      bias[t] = bv[t];
    else if (t < 192) bias[t] = boff[t-128];
    else if (t < 224) bias[t] = battn[t-192];
    __syncthreads();

    const int lane = t & 63;
    const int wave = t >> 6;
    const int ln   = lane & 15;        // A row / B col / D col within tile
    const int lk   = (lane >> 4) * 8;  // k offset within 32-chunk
    const int drow = (lane >> 4) * 4;  // D row base

    const int row_base = blockIdx.x * 256 + wave * 64;

    bf16x8 a[4][4];
    #pragma unroll
    for (int ti = 0; ti < 4; ++ti) {
        const float* ap = query + (size_t)(row_base + ti*16 + ln) * CDIM + lk;
        #pragma unroll
        for (int kc = 0; kc < 4; ++kc)
            a[ti][kc] = cvt_bf16x8(ap + kc*32);
    }

    #pragma unroll 1
    for (int cb = 0; cb < 14; ++cb) {
        const int n0 = cb * 16;
        bf16x8 bfrag[4];
        const bf16_t* bp = &Bt[n0 + ln][lk];
        #pragma unroll
        for (int kc = 0; kc < 4; ++kc)
            bfrag[kc] = *(const bf16x8*)(bp + kc*32);
        const int   col = n0 + ln;
        const float bi  = bias[col];

        #pragma unroll
        for (int ti = 0; ti < 4; ++ti) {
            f32x4 acc = {0.f, 0.f, 0.f, 0.f};
            #pragma unroll
            for (int kc = 0; kc < 4; ++kc)
                acc = __builtin_amdgcn_mfma_f32_16x16x32_bf16(a[ti][kc], bfrag[kc], acc, 0, 0, 0);
            const int r0 = row_base + ti*16 + drow;
            if (col < 128) {
                #pragma unroll
                for (int r = 0; r < 4; ++r)
                    value[(size_t)(r0 + r)*CDIM + col] = (bf16_t)(acc[r] + bi);
            } else if (col < 192) {
                #pragma unroll
                for (int r = 0; r < 4; ++r)
                    off[(size_t)(r0 + r)*64 + (col - 128)] = acc[r] + bi;
            } else {
                #pragma unroll
                for (int r = 0; r < 4; ++r)
                    attnl[(size_t)(r0 + r)*32 + (col - 192)] = acc[r] + bi;
            }
        }
    }
}

// ---------------------------------------------------------------------------
// Kernel 2: softmax over P + bilinear deformable sampling.
// One thread per (b,q,h) handling all 16 head channels.
// sampled (bf16, 256B/row) is written OVER the off region (fp32, 256B/row):
// each thread reads its own 32B of offsets before writing the same 32B.
// ---------------------------------------------------------------------------
__global__ __launch_bounds__(256)
void sample_kernel(const bf16_t* __restrict__ value, const float* off_,
                   const float* __restrict__ attnl, bf16_t* sampled)
{
    const int unit = blockIdx.x * 256 + threadIdx.x;   // (b*NQ+q)*NH + h
    const int bq   = unit >> 3;                        // b*NQ + q
    const int h    = unit & 7;
    const int q    = bq & (NQ - 1);
    const int b    = bq >> 14;

    // softmax over the 4 points (once per unit)
    const float4 lg = *(const float4*)(attnl + (size_t)bq*32 + h*4);
    float mx = fmaxf(fmaxf(lg.x, lg.y), fmaxf(lg.z, lg.w));
    float e0 = __expf(lg.x-mx), e1 = __expf(lg.y-mx), e2 = __expf(lg.z-mx), e3 = __expf(lg.w-mx);
    float rs = 1.0f / (e0 + e1 + e2 + e3);
    float aw[4] = {e0*rs, e1*rs, e2*rs, e3*rs};

    const float4 o01 = *(const float4*)(off_ + (size_t)bq*64 + h*8);
    const float4 o23 = *(const float4*)(off_ + (size_t)bq*64 + h*8 + 4);
    float ox[4] = {o01.x, o01.z, o23.x, o23.z};
    float oy[4] = {o01.y, o01.w, o23.y, o23.w};

    const float bx = (float)(q & 127) * (128.0f/127.0f) - 0.5f;
    const float by = (float)(q >> 7)  * (128.0f/127.0f) - 0.5f;

    const bf16_t* vbase = value + (size_t)b*NQ*CDIM + h*HD;

    float acc[16];
    #pragma unroll
    for (int c = 0; c < 16; ++c) acc[c] = 0.f;

    #pragma unroll
    for (int p = 0; p < 4; ++p) {
        float x = bx + ox[p];
        float y = by + oy[p];
        float xf = floorf(x), yf = floorf(y);
        int   x0 = (int)xf,  y0 = (int)yf;
        float wx1 = x - xf, wy1 = y - yf;
        float wx0 = 1.0f - wx1, wy0 = 1.0f - wy1;

        #pragma unroll
        for (int ty = 0; ty < 2; ++ty) {
            #pragma unroll
            for (int tx = 0; tx < 2; ++tx) {
                int xi = x0 + tx, yi = y0 + ty;
                float w = aw[p] * (tx ? wx1 : wx0) * (ty ? wy1 : wy0);
                bool valid = ((unsigned)xi < 128u) && ((unsigned)yi < 128u);
                float wv = valid ? w : 0.0f;
                int xc = min(max(xi, 0), 127), yc = min(max(yi, 0), 127);
                int idx = (yc << 7) | xc;                // 32-bit index math
                const bf16_t* vp = vbase + (idx << 7);   // idx*CDIM
                union { bf16x8 v; u32 d[4]; } lo, hi;
                lo.v = *(const bf16x8*)vp;
                hi.v = *(const bf16x8*)(vp + 8);
                #pragma unroll
                for (int j = 0; j < 4; ++j) {
                    u32 pl = lo.d[j];
                    acc[2*j+0] += wv * __uint_as_float(pl << 16);
                    acc[2*j+1] += wv * __uint_as_float(pl & 0xffff0000u);
                    u32 ph = hi.d[j];
                    acc[8+2*j+0] += wv * __uint_as_float(ph << 16);
                    acc[8+2*j+1] += wv * __uint_as_float(ph & 0xffff0000u);
                }
            }
        }
    }

    union { bf16x8 v; u32 d[4]; } s0, s1;
    #pragma unroll
    for (int c = 0; c < 8; ++c) { s0.v[c] = (bf16_t)acc[c]; s1.v[c] = (bf16_t)acc[8+c]; }
    bf16_t* sp = sampled + (size_t)bq*CDIM + h*HD;   // overlays off_ bytes of THIS thread
    *(bf16x8*)sp       = s0.v;
    *(bf16x8*)(sp + 8) = s1.v;
}

// ---------------------------------------------------------------------------
// Kernel 3: out = sampled(bf16) @ Wout + bout + 2*query   (fp32 out)
// ---------------------------------------------------------------------------
__global__ __launch_bounds__(256, 2)
void out_kernel(const bf16_t* __restrict__ sampled, const float* __restrict__ Wout,
                const float* __restrict__ bout, const float* __restrict__ query,
                float* __restrict__ out)
{
    __shared__ bf16_t Bt[128][136];
    __shared__ float  bias[128];
    const int t = threadIdx.x;

    for (int i = t; i < 128*128; i += 256) { int k = i >> 7, n = i & 127; Bt[n][k] = (bf16_t)Wout[i]; }
    if (t < 128) bias[t] = bout[t];
    __syncthreads();

    const int lane = t & 63;
    const int wave = t >> 6;
    const int ln   = lane & 15;
    const int lk   = (lane >> 4) * 8;
    const int drow = (lane >> 4) * 4;

    const int row_base = blockIdx.x * 256 + wave * 64;

    bf16x8 a[4][4];
    #pragma unroll
    for (int ti = 0; ti < 4; ++ti) {
        const bf16_t* ap = sampled + (size_t)(row_base + ti*16 + ln) * CDIM + lk;
        #pragma unroll
        for (int kc = 0; kc < 4; ++kc)
            a[ti][kc] = *(const bf16x8*)(ap + kc*32);
    }

    #pragma unroll 1
    for (int cb = 0; cb < 8; ++cb) {
        const int n0 = cb * 16;
        bf16x8 bfrag[4];
        const bf16_t* bp = &Bt[n0 + ln][lk];
        #pragma unroll
        for (int kc = 0; kc < 4; ++kc)
            bfrag[kc] = *(const bf16x8*)(bp + kc*32);
        const int   col = n0 + ln;
        const float bi  = bias[col];

        #pragma unroll
        for (int ti = 0; ti < 4; ++ti) {
            f32x4 acc = {0.f, 0.f, 0.f, 0.f};
            #pragma unroll
            for (int kc = 0; kc < 4; ++kc)
                acc = __builtin_amdgcn_mfma_f32_16x16x32_bf16(a[ti][kc], bfrag[kc], acc, 0, 0, 0);
            const int r0 = row_base + ti*16 + drow;
            #pragma unroll
            for (int r = 0; r < 4; ++r) {
                const size_t qi = (size_t)(r0 + r)*CDIM + col;
                out[qi] = acc[r] + bi + 2.0f * query[qi];
            }
        }
    }
}

// ---------------------------------------------------------------------------
extern "C" void kernel_launch(void* const* d_in, const int* in_sizes, int n_in,
                              void* d_out, int out_size, void* d_ws, size_t ws_size,
                              hipStream_t stream)
{
    const float* query = (const float*)d_in[0];
    const float* Wv    = (const float*)d_in[1];
    const float* bv    = (const float*)d_in[2];
    const float* Woff  = (const float*)d_in[3];
    const float* boff  = (const float*)d_in[4];
    const float* Wattn = (const float*)d_in[5];
    const float* battn = (const float*)d_in[6];
    const float* Wout  = (const float*)d_in[7];
    const float* bout  = (const float*)d_in[8];
    float* out = (float*)d_out;

    // ws layout: value bf16 (33.5MB) | off fp32 (33.5MB, later overlaid by
    // sampled bf16 with identical 256B/row layout) | attnl fp32 (16.8MB)
    bf16_t* value = (bf16_t*)d_ws;
    float*  off   = (float*)((char*)d_ws + (size_t)M_TOTAL*CDIM*2);
    float*  attnl = (float*)((char*)d_ws + (size_t)M_TOTAL*CDIM*2 + (size_t)M_TOTAL*64*4);
    bf16_t* sampled = (bf16_t*)off;   // aliased by design (per-thread RAW only)

    proj_kernel<<<M_TOTAL/256, 256, 0, stream>>>(query, Wv, bv, Woff, boff,
                                                 Wattn, battn, value, off, attnl);
    sample_kernel<<<(BS*NQ*NH)/256, 256, 0, stream>>>(value, off, attnl, sampled);
    out_kernel<<<M_TOTAL/256, 256, 0, stream>>>(sampled, Wout, bout, query, out);
}

// Round 4
// 238.609 us; speedup vs baseline: 1.1563x; 1.1563x over previous
//
#include <hip/hip_runtime.h>
#include <hip/hip_bf16.h>

#define BS    8
#define NQ    16384
#define CDIM  128
#define NH    8
#define NP    4
#define HD    16
#define RES   128
#define NPROJ 224            // 128 value + 64 off + 32 attn logits
#define M_TOTAL (BS*NQ)      // 131072 rows

typedef __bf16 bf16_t;
typedef __bf16 bf16x8 __attribute__((ext_vector_type(8)));
typedef __bf16 bf16x4 __attribute__((ext_vector_type(4)));
typedef float  f32x4  __attribute__((ext_vector_type(4)));
typedef unsigned int u32;

__device__ __forceinline__ bf16x8 cvt_bf16x8(const float* p) {
    float4 a = *(const float4*)p;
    float4 b = *(const float4*)(p + 4);
    bf16x8 r;
    r[0] = (bf16_t)a.x; r[1] = (bf16_t)a.y; r[2] = (bf16_t)a.z; r[3] = (bf16_t)a.w;
    r[4] = (bf16_t)b.x; r[5] = (bf16_t)b.y; r[6] = (bf16_t)b.z; r[7] = (bf16_t)b.w;
    return r;
}

// ---------------------------------------------------------------------------
// Kernel 1: fused projections  P = query @ [Wv | Woff | Wattn] + bias
// 512 threads = 8 waves/block; each wave owns 16 rows (grid 1024 blocks ->
// 4 waves/SIMD at the 2-blocks/CU LDS limit).
// ---------------------------------------------------------------------------
__global__ __launch_bounds__(512)
void proj_kernel(const float* __restrict__ query,
                 const float* __restrict__ Wv,    const float* __restrict__ bv,
                 const float* __restrict__ Woff,  const float* __restrict__ boff,
                 const float* __restrict__ Wattn, const float* __restrict__ battn,
                 bf16_t* __restrict__ value, float* __restrict__ off,
                 float* __restrict__ attnl)
{
    __shared__ bf16_t Bt[NPROJ][136];   // transposed weights (bf16), padded
    __shared__ float  bias[NPROJ];
    const int t = threadIdx.x;

    for (int i = t; i < 128*128; i += 512) { int k = i >> 7, n = i & 127; Bt[n][k]     = (bf16_t)Wv[i]; }
    for (int i = t; i < 128*64;  i += 512) { int k = i >> 6, n = i & 63;  Bt[128+n][k] = (bf16_t)Woff[i]; }
    for (int i = t; i < 128*32;  i += 512) { int k = i >> 5, n = i & 31;  Bt[192+n][k] = (bf16_t)Wattn[i]; }
    if (t < 128)      bias[t] = bv[t];
    else if (t < 192) bias[t] = boff[t-128];
    else if (t < 224) bias[t] = battn[t-192];
    __syncthreads();

    const int lane = t & 63;
    const int wave = t >> 6;           // 0..7
    const int ln   = lane & 15;        // A row / D col within tile
    const int lk   = (lane >> 4) * 8;  // k offset within 32-chunk
    const int drow = (lane >> 4) * 4;  // D row base

    const int row0 = blockIdx.x * 128 + wave * 16;   // 16 rows per wave

    bf16x8 a[4];
    const float* ap = query + (row0 + ln) * CDIM + lk;
    #pragma unroll
    for (int kc = 0; kc < 4; ++kc)
        a[kc] = cvt_bf16x8(ap + kc*32);

    #pragma unroll 1
    for (int cb = 0; cb < 14; ++cb) {
        const int n0 = cb * 16;
        bf16x8 bfrag[4];
        const bf16_t* bp = &Bt[n0 + ln][lk];
        #pragma unroll
        for (int kc = 0; kc < 4; ++kc)
            bfrag[kc] = *(const bf16x8*)(bp + kc*32);
        const int   col = n0 + ln;
        const float bi  = bias[col];

        f32x4 acc = {0.f, 0.f, 0.f, 0.f};
        #pragma unroll
        for (int kc = 0; kc < 4; ++kc)
            acc = __builtin_amdgcn_mfma_f32_16x16x32_bf16(a[kc], bfrag[kc], acc, 0, 0, 0);

        const int r0 = row0 + drow;
        if (cb < 8) {              // value region (wave-uniform branch)
            #pragma unroll
            for (int r = 0; r < 4; ++r)
                value[(r0 + r)*CDIM + col] = (bf16_t)(acc[r] + bi);
        } else if (cb < 12) {      // offsets region
            #pragma unroll
            for (int r = 0; r < 4; ++r)
                off[(r0 + r)*64 + (col - 128)] = acc[r] + bi;
        } else {                   // attn-logits region
            #pragma unroll
            for (int r = 0; r < 4; ++r)
                attnl[(r0 + r)*32 + (col - 192)] = acc[r] + bi;
        }
    }
}

// ---------------------------------------------------------------------------
// Kernel 2: softmax over P + bilinear sampling. 4 lanes per (b,q,h); lane j
// owns channels [4j..4j+4). Quad's 4x8B tap loads are 32B contiguous.
// sampled (bf16, 256B/row) overlays the off region (fp32, 256B/row): every
// lane's off loads complete (data dependence) before its store issues.
// ---------------------------------------------------------------------------
__global__ __launch_bounds__(256)
void sample_kernel(const bf16_t* __restrict__ value, const float* off_,
                   const float* __restrict__ attnl, bf16_t* sampled)
{
    const int tid  = blockIdx.x * 256 + threadIdx.x;   // BS*NQ*NH*4 threads
    const int j    = tid & 3;                          // channel quarter
    const int unit = tid >> 2;                         // (b*NQ+q)*NH + h
    const int h    = unit & 7;
    const int bq   = unit >> 3;                        // b*NQ + q
    const int q    = bq & (NQ - 1);
    const int b    = bq >> 14;

    // softmax over the 4 points
    const float4 lg = *(const float4*)(attnl + bq*32 + h*4);
    float mx = fmaxf(fmaxf(lg.x, lg.y), fmaxf(lg.z, lg.w));
    float e0 = __expf(lg.x-mx), e1 = __expf(lg.y-mx), e2 = __expf(lg.z-mx), e3 = __expf(lg.w-mx);
    float rs = 1.0f / (e0 + e1 + e2 + e3);
    float aw[4] = {e0*rs, e1*rs, e2*rs, e3*rs};

    const float4 o01 = *(const float4*)(off_ + bq*64 + h*8);
    const float4 o23 = *(const float4*)(off_ + bq*64 + h*8 + 4);
    float ox[4] = {o01.x, o01.z, o23.x, o23.z};
    float oy[4] = {o01.y, o01.w, o23.y, o23.w};

    const float bx = (float)(q & 127) * (128.0f/127.0f) - 0.5f;
    const float by = (float)(q >> 7)  * (128.0f/127.0f) - 0.5f;

    const bf16_t* vbase = value + b*NQ*CDIM + h*HD + j*4;

    float a0 = 0.f, a1 = 0.f, a2 = 0.f, a3 = 0.f;
    #pragma unroll
    for (int p = 0; p < 4; ++p) {
        float x = bx + ox[p];
        float y = by + oy[p];
        float xf = floorf(x), yf = floorf(y);
        int   x0 = (int)xf,  y0 = (int)yf;
        float wx1 = x - xf, wy1 = y - yf;
        // validity folded into edge weights (zero weight outside the map)
        float wxe0 = (((unsigned)x0       < 128u) ? (1.0f - wx1) : 0.f);
        float wxe1 = (((unsigned)(x0 + 1) < 128u) ? wx1          : 0.f);
        float wye0 = (((unsigned)y0       < 128u) ? (1.0f - wy1) : 0.f) * aw[p];
        float wye1 = (((unsigned)(y0 + 1) < 128u) ? wy1          : 0.f) * aw[p];
        int xc0 = min(max(x0, 0), 127),     xc1 = min(max(x0 + 1, 0), 127);
        int rb0 = min(max(y0, 0), 127) << 7, rb1 = min(max(y0 + 1, 0), 127) << 7;

        const int   idx[4] = {rb0 + xc0, rb0 + xc1, rb1 + xc0, rb1 + xc1};
        const float wt [4] = {wxe0*wye0, wxe1*wye0, wxe0*wye1, wxe1*wye1};
        #pragma unroll
        for (int tp = 0; tp < 4; ++tp) {
            const uint2 d = *(const uint2*)(vbase + (idx[tp] << 7));
            const float w = wt[tp];
            a0 += w * __uint_as_float(d.x << 16);
            a1 += w * __uint_as_float(d.x & 0xffff0000u);
            a2 += w * __uint_as_float(d.y << 16);
            a3 += w * __uint_as_float(d.y & 0xffff0000u);
        }
    }

    bf16x4 s;
    s[0] = (bf16_t)a0; s[1] = (bf16_t)a1; s[2] = (bf16_t)a2; s[3] = (bf16_t)a3;
    *(bf16x4*)(sampled + bq*CDIM + h*HD + j*4) = s;   // overlays this lane's off bytes
}

// ---------------------------------------------------------------------------
// Kernel 3: out = sampled(bf16) @ Wout + bout + 2*query   (fp32 out)
// 512 threads = 8 waves; each wave 16 rows; grid 1024 blocks.
// LDS 35KB -> 4 blocks/CU possible.
// ---------------------------------------------------------------------------
__global__ __launch_bounds__(512)
void out_kernel(const bf16_t* __restrict__ sampled, const float* __restrict__ Wout,
                const float* __restrict__ bout, const float* __restrict__ query,
                float* __restrict__ out)
{
    __shared__ bf16_t Bt[128][136];
    __shared__ float  bias[128];
    const int t = threadIdx.x;

    for (int i = t; i < 128*128; i += 512) { int k = i >> 7, n = i & 127; Bt[n][k] = (bf16_t)Wout[i]; }
    if (t < 128) bias[t] = bout[t];
    __syncthreads();

    const int lane = t & 63;
    const int wave = t >> 6;
    const int ln   = lane & 15;
    const int lk   = (lane >> 4) * 8;
    const int drow = (lane >> 4) * 4;

    const int row0 = blockIdx.x * 128 + wave * 16;

    bf16x8 a[4];
    const bf16_t* apb = sampled + (row0 + ln) * CDIM + lk;
    #pragma unroll
    for (int kc = 0; kc < 4; ++kc)
        a[kc] = *(const bf16x8*)(apb + kc*32);

    #pragma unroll 1
    for (int cb = 0; cb < 8; ++cb) {
        const int n0 = cb * 16;
        bf16x8 bfrag[4];
        const bf16_t* bp = &Bt[n0 + ln][lk];
        #pragma unroll
        for (int kc = 0; kc < 4; ++kc)
            bfrag[kc] = *(const bf16x8*)(bp + kc*32);
        const int   col = n0 + ln;
        const float bi  = bias[col];

        f32x4 acc = {0.f, 0.f, 0.f, 0.f};
        #pragma unroll
        for (int kc = 0; kc < 4; ++kc)
            acc = __builtin_amdgcn_mfma_f32_16x16x32_bf16(a[kc], bfrag[kc], acc, 0, 0, 0);

        const int r0 = row0 + drow;
        #pragma unroll
        for (int r = 0; r < 4; ++r) {
            const int qi = (r0 + r)*CDIM + col;
            out[qi] = acc[r] + bi + 2.0f * query[qi];
        }
    }
}

// ---------------------------------------------------------------------------
extern "C" void kernel_launch(void* const* d_in, const int* in_sizes, int n_in,
                              void* d_out, int out_size, void* d_ws, size_t ws_size,
                              hipStream_t stream)
{
    const float* query = (const float*)d_in[0];
    const float* Wv    = (const float*)d_in[1];
    const float* bv    = (const float*)d_in[2];
    const float* Woff  = (const float*)d_in[3];
    const float* boff  = (const float*)d_in[4];
    const float* Wattn = (const float*)d_in[5];
    const float* battn = (const float*)d_in[6];
    const float* Wout  = (const float*)d_in[7];
    const float* bout  = (const float*)d_in[8];
    float* out = (float*)d_out;

    // ws layout: value bf16 (33.5MB) | off fp32 (33.5MB, later overlaid by
    // sampled bf16 with identical 256B/row layout) | attnl fp32 (16.8MB)
    bf16_t* value = (bf16_t*)d_ws;
    float*  off   = (float*)((char*)d_ws + (size_t)M_TOTAL*CDIM*2);
    float*  attnl = (float*)((char*)d_ws + (size_t)M_TOTAL*CDIM*2 + (size_t)M_TOTAL*64*4);
    bf16_t* sampled = (bf16_t*)off;   // aliased by design (per-lane RAW only)

    proj_kernel<<<M_TOTAL/128, 512, 0, stream>>>(query, Wv, bv, Woff, boff,
                                                 Wattn, battn, value, off, attnl);
    sample_kernel<<<(BS*NQ*NH*4)/256, 256, 0, stream>>>(value, off, attnl, sampled);
    out_kernel<<<M_TOTAL/128, 512, 0, stream>>>(sampled, Wout, bout, query, out);
}

// Round 5
// 211.227 us; speedup vs baseline: 1.3062x; 1.1296x over previous
//
#include <hip/hip_runtime.h>
#include <hip/hip_bf16.h>

#define BS    8
#define NQ    16384
#define CDIM  128
#define NH    8
#define NPROJ 224            // 128 value + 64 off + 32 attn logits
#define M_TOTAL (BS*NQ)      // 131072 rows

typedef __bf16 bf16_t;
typedef __bf16 bf16x8 __attribute__((ext_vector_type(8)));
typedef __bf16 bf16x4 __attribute__((ext_vector_type(4)));
typedef float  f32x4  __attribute__((ext_vector_type(4)));
typedef unsigned int u32;

__device__ __forceinline__ bf16x8 cvt_bf16x8(const float* p) {
    float4 a = *(const float4*)p;
    float4 b = *(const float4*)(p + 4);
    bf16x8 r;
    r[0] = (bf16_t)a.x; r[1] = (bf16_t)a.y; r[2] = (bf16_t)a.z; r[3] = (bf16_t)a.w;
    r[4] = (bf16_t)b.x; r[5] = (bf16_t)b.y; r[6] = (bf16_t)b.z; r[7] = (bf16_t)b.w;
    return r;
}
__device__ __forceinline__ float bflo(u32 d) { return __uint_as_float(d << 16); }
__device__ __forceinline__ float bfhi(u32 d) { return __uint_as_float(d & 0xffff0000u); }

// ---------------------------------------------------------------------------
// Kernel 1: fused projections  P = query @ [Wv | Woff | Wattn] + bias
// Operand-swapped MFMA: A-operand = W^T tile, B-operand = query rows.
// D: lane(q4,ln) holds channels n0+4*q4+{0..3} of query row row0+ln
//  -> packed bf16x4 stores (value / off / attn all bf16).
// ---------------------------------------------------------------------------
__global__ __launch_bounds__(512, 4)
void proj_kernel(const float* __restrict__ query,
                 const float* __restrict__ Wv,    const float* __restrict__ bv,
                 const float* __restrict__ Woff,  const float* __restrict__ boff,
                 const float* __restrict__ Wattn, const float* __restrict__ battn,
                 bf16_t* __restrict__ value, bf16_t* __restrict__ offb,
                 bf16_t* __restrict__ attnb)
{
    __shared__ bf16_t Bt[NPROJ][136];   // Bt[n][k] = W[k][n], padded (2-way free)
    __shared__ float  bias[NPROJ];
    const int t = threadIdx.x;

    for (int i = t; i < 128*128; i += 512) { int k = i >> 7, n = i & 127; Bt[n][k]     = (bf16_t)Wv[i]; }
    for (int i = t; i < 128*64;  i += 512) { int k = i >> 6, n = i & 63;  Bt[128+n][k] = (bf16_t)Woff[i]; }
    for (int i = t; i < 128*32;  i += 512) { int k = i >> 5, n = i & 31;  Bt[192+n][k] = (bf16_t)Wattn[i]; }
    if (t < 128)      bias[t] = bv[t];
    else if (t < 192) bias[t] = boff[t-128];
    else if (t < 224) bias[t] = battn[t-192];
    __syncthreads();

    const int lane = t & 63;
    const int wave = t >> 6;           // 0..7
    const int ln   = lane & 15;
    const int q4   = lane >> 4;
    const int lk   = q4 * 8;

    const int row = blockIdx.x * 128 + wave * 16 + ln;   // this lane's query row

    // B-operand: query row fragments (fp32 -> bf16)
    bf16x8 qf[4];
    const float* ap = query + row * CDIM + lk;
    #pragma unroll
    for (int kc = 0; kc < 4; ++kc)
        qf[kc] = cvt_bf16x8(ap + kc*32);

    #pragma unroll 1
    for (int cb = 0; cb < 14; ++cb) {
        const int n0 = cb * 16;
        bf16x8 wf[4];
        const bf16_t* bp = &Bt[n0 + ln][lk];   // A-operand: channel n0+ln
        #pragma unroll
        for (int kc = 0; kc < 4; ++kc)
            wf[kc] = *(const bf16x8*)(bp + kc*32);

        f32x4 acc = {0.f, 0.f, 0.f, 0.f};
        #pragma unroll
        for (int kc = 0; kc < 4; ++kc)
            acc = __builtin_amdgcn_mfma_f32_16x16x32_bf16(wf[kc], qf[kc], acc, 0, 0, 0);

        const int c0 = n0 + q4*4;              // first of 4 consecutive channels
        const f32x4 bi = *(const f32x4*)&bias[c0];
        bf16x4 s;
        #pragma unroll
        for (int r = 0; r < 4; ++r) s[r] = (bf16_t)(acc[r] + bi[r]);

        if (cb < 8) {
            *(bf16x4*)(value + row*CDIM + c0) = s;
        } else if (cb < 12) {
            *(bf16x4*)(offb + row*64 + (c0 - 128)) = s;
        } else {
            *(bf16x4*)(attnb + row*32 + (c0 - 192)) = s;
        }
    }
}

// ---------------------------------------------------------------------------
// Kernel 2 (fused sample + out-proj):
// Phase 1: 64 query rows/block; 4 lanes per (row,h) unit, each thread loops
//          4 units. Softmax + 16 bilinear taps -> sampled row tile in LDS.
// Phase 2: operand-swapped MFMA vs Wout^T in LDS; epilogue +bout+2*query,
//          packed float4 stores.
// ---------------------------------------------------------------------------
__global__ __launch_bounds__(512, 4)
void sample_out_kernel(const bf16_t* __restrict__ value, const bf16_t* __restrict__ offb,
                       const bf16_t* __restrict__ attnb, const float* __restrict__ Wout,
                       const float* __restrict__ bout, const float* __restrict__ query,
                       float* __restrict__ out)
{
    __shared__ bf16_t Wt[128][136];     // Wout^T
    __shared__ float  bias[128];
    __shared__ bf16_t Srow[64][136];    // sampled rows tile (pad 8)
    const int t = threadIdx.x;

    for (int i = t; i < 128*128; i += 512) { int k = i >> 7, n = i & 127; Wt[n][k] = (bf16_t)Wout[i]; }
    if (t < 128) bias[t] = bout[t];

    const int row_base = blockIdx.x * 64;
    const int j  = t & 3;              // channel quarter within unit
    const int uq = t >> 2;             // 0..127

    #pragma unroll 1
    for (int u = 0; u < 4; ++u) {
        const int unit = u*128 + uq;   // 0..511 = 64 rows x 8 heads
        const int lr   = unit >> 3;
        const int h    = unit & 7;
        const int bq   = row_base + lr;
        const int q    = bq & (NQ - 1);
        const int b    = bq >> 14;

        // softmax over 4 points (logits bf16; |l| < ~2, no max-sub needed)
        union { bf16x4 v; u32 d[2]; } at;
        at.v = *(const bf16x4*)(attnb + bq*32 + h*4);
        float e0 = __expf(bflo(at.d[0])), e1 = __expf(bfhi(at.d[0]));
        float e2 = __expf(bflo(at.d[1])), e3 = __expf(bfhi(at.d[1]));
        float rs = 1.0f / (e0 + e1 + e2 + e3);
        const float aw[4] = {e0*rs, e1*rs, e2*rs, e3*rs};

        union { bf16x8 v; u32 d[4]; } of;
        of.v = *(const bf16x8*)(offb + bq*64 + h*8);

        const float bx = (float)(q & 127) * (128.0f/127.0f) - 0.5f;
        const float by = (float)(q >> 7)  * (128.0f/127.0f) - 0.5f;

        const bf16_t* vbase = value + b*NQ*CDIM + h*16 + j*4;

        float a0 = 0.f, a1 = 0.f, a2 = 0.f, a3 = 0.f;
        #pragma unroll
        for (int p = 0; p < 4; ++p) {
            float x = bx + bflo(of.d[p]);
            float y = by + bfhi(of.d[p]);
            float xf = floorf(x), yf = floorf(y);
            int   x0 = (int)xf,  y0 = (int)yf;
            float wx1 = x - xf, wy1 = y - yf;
            float wxe0 = (((unsigned)x0       < 128u) ? (1.0f - wx1) : 0.f);
            float wxe1 = (((unsigned)(x0 + 1) < 128u) ? wx1          : 0.f);
            float wye0 = (((unsigned)y0       < 128u) ? (1.0f - wy1) : 0.f) * aw[p];
            float wye1 = (((unsigned)(y0 + 1) < 128u) ? wy1          : 0.f) * aw[p];
            int xc0 = min(max(x0, 0), 127),      xc1 = min(max(x0 + 1, 0), 127);
            int rb0 = min(max(y0, 0), 127) << 7, rb1 = min(max(y0 + 1, 0), 127) << 7;

            const int   idx[4] = {rb0 + xc0, rb0 + xc1, rb1 + xc0, rb1 + xc1};
            const float wt [4] = {wxe0*wye0, wxe1*wye0, wxe0*wye1, wxe1*wye1};
            #pragma unroll
            for (int tp = 0; tp < 4; ++tp) {
                const uint2 d = *(const uint2*)(vbase + (idx[tp] << 7));
                const float w = wt[tp];
                a0 += w * bflo(d.x);
                a1 += w * bfhi(d.x);
                a2 += w * bflo(d.y);
                a3 += w * bfhi(d.y);
            }
        }
        bf16x4 s;
        s[0] = (bf16_t)a0; s[1] = (bf16_t)a1; s[2] = (bf16_t)a2; s[3] = (bf16_t)a3;
        *(bf16x4*)(&Srow[lr][h*16 + j*4]) = s;
    }
    __syncthreads();

    // Phase 2: 8 waves x 4 jobs: row-tile rt = wave>>1, col-blocks (wave&1)*4..+3
    const int lane = t & 63;
    const int wave = t >> 6;
    const int ln   = lane & 15;
    const int q4   = lane >> 4;
    const int lk   = q4 * 8;
    const int rt   = wave >> 1;
    const int cb0  = (wave & 1) * 4;

    bf16x8 sf[4];
    const bf16_t* sp = &Srow[rt*16 + ln][lk];   // B-operand: sampled row
    #pragma unroll
    for (int kc = 0; kc < 4; ++kc)
        sf[kc] = *(const bf16x8*)(sp + kc*32);

    const int grow = row_base + rt*16 + ln;     // global row this lane stores

    #pragma unroll
    for (int c = 0; c < 4; ++c) {
        const int n0 = (cb0 + c) * 16;
        bf16x8 wf[4];
        const bf16_t* bp = &Wt[n0 + ln][lk];    // A-operand: out channel n0+ln
        #pragma unroll
        for (int kc = 0; kc < 4; ++kc)
            wf[kc] = *(const bf16x8*)(bp + kc*32);

        f32x4 acc = {0.f, 0.f, 0.f, 0.f};
        #pragma unroll
        for (int kc = 0; kc < 4; ++kc)
            acc = __builtin_amdgcn_mfma_f32_16x16x32_bf16(wf[kc], sf[kc], acc, 0, 0, 0);

        const int c0 = n0 + q4*4;
        const f32x4 bi = *(const f32x4*)&bias[c0];
        const float4 qv = *(const float4*)(query + grow*CDIM + c0);
        float4 o;
        o.x = acc[0] + bi[0] + 2.0f*qv.x;
        o.y = acc[1] + bi[1] + 2.0f*qv.y;
        o.z = acc[2] + bi[2] + 2.0f*qv.z;
        o.w = acc[3] + bi[3] + 2.0f*qv.w;
        *(float4*)(out + grow*CDIM + c0) = o;
    }
}

// ---------------------------------------------------------------------------
extern "C" void kernel_launch(void* const* d_in, const int* in_sizes, int n_in,
                              void* d_out, int out_size, void* d_ws, size_t ws_size,
                              hipStream_t stream)
{
    const float* query = (const float*)d_in[0];
    const float* Wv    = (const float*)d_in[1];
    const float* bv    = (const float*)d_in[2];
    const float* Woff  = (const float*)d_in[3];
    const float* boff  = (const float*)d_in[4];
    const float* Wattn = (const float*)d_in[5];
    const float* battn = (const float*)d_in[6];
    const float* Wout  = (const float*)d_in[7];
    const float* bout  = (const float*)d_in[8];
    float* out = (float*)d_out;

    // ws: value bf16 (33.5MB) | off bf16 (16.8MB) | attnl bf16 (8.4MB)
    bf16_t* value = (bf16_t*)d_ws;
    bf16_t* offb  = (bf16_t*)((char*)d_ws + (size_t)M_TOTAL*CDIM*2);
    bf16_t* attnb = (bf16_t*)((char*)d_ws + (size_t)M_TOTAL*CDIM*2 + (size_t)M_TOTAL*64*2);

    proj_kernel<<<M_TOTAL/128, 512, 0, stream>>>(query, Wv, bv, Woff, boff,
                                                 Wattn, battn, value, offb, attnb);
    sample_out_kernel<<<M_TOTAL/64, 512, 0, stream>>>(value, offb, attnb,
                                                      Wout, bout, query, out);
}